// Round 1
// baseline (818.080 us; speedup 1.0000x reference)
//
#include <hip/hip_runtime.h>
#include <stdint.h>

#define B_ 512
#define D_ 512
#define C_ 100000
#define CK_ 300000
#define S_ 30.0f
#define COSM_ 0.8775825618903728f
#define SINM_ 0.4794255386042030f
#define TH_ (-0.8775825618903728f)
#define MM_ 0.2397127693021015f
#define EPS_ 1e-12f

#define BM 128
#define BN 96
#define BK 32
#define NCLS 32   /* classes per column tile */

typedef float f32x4 __attribute__((ext_vector_type(4)));
typedef short s16x8 __attribute__((ext_vector_type(8)));
typedef unsigned long long u64;
typedef unsigned int u32;
typedef unsigned short ushort_t;

__device__ __forceinline__ unsigned short f2bf(float f){
  u32 u = __float_as_uint(f);
  u += 0x7FFFu + ((u >> 16) & 1u);   // round-to-nearest-even
  return (unsigned short)(u >> 16);
}

// ---------------- normalize x rows -> bf16 ----------------
__global__ void k_normx(const float* __restrict__ x, unsigned short* __restrict__ xn){
  int row  = blockIdx.x * 4 + (threadIdx.x >> 6);
  int lane = threadIdx.x & 63;
  const float* xr = x + (size_t)row * D_ + lane * 8;
  float4 v0 = *(const float4*)xr;
  float4 v1 = *(const float4*)(xr + 4);
  float s = v0.x*v0.x + v0.y*v0.y + v0.z*v0.z + v0.w*v0.w
          + v1.x*v1.x + v1.y*v1.y + v1.z*v1.z + v1.w*v1.w;
  #pragma unroll
  for (int off = 1; off < 64; off <<= 1) s += __shfl_xor(s, off);
  float inv = 1.f / fmaxf(sqrtf(s), EPS_);
  s16x8 h;
  h[0] = (short)f2bf(v0.x*inv); h[1] = (short)f2bf(v0.y*inv);
  h[2] = (short)f2bf(v0.z*inv); h[3] = (short)f2bf(v0.w*inv);
  h[4] = (short)f2bf(v1.x*inv); h[5] = (short)f2bf(v1.y*inv);
  h[6] = (short)f2bf(v1.z*inv); h[7] = (short)f2bf(v1.w*inv);
  *(s16x8*)(xn + (size_t)row * D_ + lane * 8) = h;
}

// ---------------- zero the per-row reduction buffers ----------------
__global__ void k_init(float* __restrict__ sumexp, u64* __restrict__ packed,
                       float* __restrict__ phi){
  int i = threadIdx.x;
  sumexp[i] = 0.f;
  packed[i] = 0ull;
  phi[i]    = 0.f;
}

// ---------------- fused GEMM + norm + subcenter-max + lse/argmax ----------------
__global__ __launch_bounds__(256) void k_gemm(
    const unsigned short* __restrict__ xn, const float* __restrict__ w,
    const int* __restrict__ label,
    float* __restrict__ sumexp_g, u64* __restrict__ packed_g,
    float* __restrict__ phi_g)
{
  __shared__ union {
    struct { unsigned short a[BM*BK]; unsigned short b[BN*BK]; } st;
    float cs[BM*100];                       // cos tile, padded stride 100
  } sm;
  __shared__ float invs[BN];

  const int bid     = blockIdx.x;
  const int ct      = bid >> 2;             // 0..3124  (column tile, 4 sharers adjacent)
  const int rt      = bid & 3;              // 0..3     (row tile)
  const int rowbase = rt * BM;
  const int colbase = ct * BN;

  const int tid  = threadIdx.x;
  const int lane = tid & 63;
  const int wid  = tid >> 6;
  const int wm   = wid >> 1, wn = wid & 1;  // 2x2 wave grid, wave tile 64x48

  f32x4 acc[4][3] = {};
  float sq[3] = {0.f, 0.f, 0.f};

  for (int kt = 0; kt < D_/BK; ++kt){
    const int k0 = kt * BK;
    // stage A (bf16 xn): 128x32 = 2 passes of 256 x 16B
    #pragma unroll
    for (int p = 0; p < 2; ++p){
      int fl = p*256 + tid;
      int ar = fl >> 2, ac = (fl & 3) * 8;
      s16x8 v = *(const s16x8*)(xn + (size_t)(rowbase + ar) * D_ + k0 + ac);
      *(s16x8*)(&sm.st.a[ar*BK + ac]) = v;
    }
    // stage B (weight rows fp32 -> bf16) + in-flight sum of squares
    #pragma unroll
    for (int p = 0; p < 3; ++p){
      int fl = p*256 + tid;
      int br = fl >> 3, bc = (fl & 7) * 4;
      float4 v = *(const float4*)(w + (size_t)(colbase + br) * D_ + k0 + bc);
      sq[p] += v.x*v.x + v.y*v.y + v.z*v.z + v.w*v.w;
      ushort4 h;
      h.x = f2bf(v.x); h.y = f2bf(v.y); h.z = f2bf(v.z); h.w = f2bf(v.w);
      *(ushort4*)(&sm.st.b[br*BK + bc]) = h;
    }
    __syncthreads();
    s16x8 af[4], bfr[3];
    #pragma unroll
    for (int m = 0; m < 4; ++m)
      af[m] = *(const s16x8*)(&sm.st.a[(wm*64 + m*16 + (lane & 15))*BK + (lane >> 4)*8]);
    #pragma unroll
    for (int n = 0; n < 3; ++n)
      bfr[n] = *(const s16x8*)(&sm.st.b[(wn*48 + n*16 + (lane & 15))*BK + (lane >> 4)*8]);
    #pragma unroll
    for (int m = 0; m < 4; ++m)
      #pragma unroll
      for (int n = 0; n < 3; ++n)
        acc[m][n] = __builtin_amdgcn_mfma_f32_16x16x32_bf16(af[m], bfr[n], acc[m][n], 0, 0, 0);
    __syncthreads();
  }

  // weight-row inverse norms: each row's sumsq is spread over 8 adjacent threads
  #pragma unroll
  for (int p = 0; p < 3; ++p){
    float s = sq[p];
    s += __shfl_xor(s, 1); s += __shfl_xor(s, 2); s += __shfl_xor(s, 4);
    if ((tid & 7) == 0) invs[p*32 + (tid >> 3)] = 1.f / fmaxf(sqrtf(s), EPS_);
  }
  __syncthreads();

  // write cos tile (scaled accumulators) to LDS
  #pragma unroll
  for (int n = 0; n < 3; ++n){
    int col = wn*48 + n*16 + (lane & 15);
    float inv = invs[col];
    #pragma unroll
    for (int m = 0; m < 4; ++m){
      int r0 = wm*64 + m*16 + (lane >> 4)*4;
      #pragma unroll
      for (int r = 0; r < 4; ++r)
        sm.cs[(r0 + r)*100 + col] = acc[m][n][r] * inv;
    }
  }
  __syncthreads();

  // per-row reduction over this block's 32 classes: 2 threads per row
  {
    int row  = tid >> 1;
    int half = tid & 1;
    int grow = rowbase + row;
    int lab  = label[grow];
    int labloc = lab - ct * NCLS;           // local class idx if inside this tile
    float se = 0.f;
    u64 pk = 0ull;
    #pragma unroll 4
    for (int c = 0; c < 16; ++c){
      int lc = half*16 + c;
      const float* p3 = &sm.cs[row*100 + lc*3];
      float v = fmaxf(fmaxf(p3[0], p3[1]), p3[2]);
      if (lc == labloc){
        float cy = v;
        float s2 = fminf(fmaxf(1.f - cy*cy, 0.f), 1.f);
        float sy = sqrtf(s2);
        float ph = cy*COSM_ - sy*SINM_;
        if (!(cy - TH_ > 0.f)) ph = cy - MM_;
        phi_g[grow] = ph;                   // unique writer
        v = ph;
      }
      se += __expf(S_*v - S_);              // shift by 30 (= S*max possible cos)
      u32 u = __float_as_uint(v);
      u = (v >= 0.f) ? (u | 0x80000000u) : ~u;   // sortable float
      u64 p = ((u64)u << 32) | (u32)~(u32)(ct*NCLS + lc);  // ~idx: first-occurrence ties
      pk = (p > pk) ? p : pk;
    }
    se += __shfl_xor(se, 1);
    u32 lo = (u32)pk, hi = (u32)(pk >> 32);
    u32 plo = __shfl_xor(lo, 1), phi2 = __shfl_xor(hi, 1);
    u64 po = ((u64)phi2 << 32) | plo;
    pk = (po > pk) ? po : pk;
    if (half == 0){
      atomicAdd(&sumexp_g[grow], se);
      atomicMax(&packed_g[grow], pk);
    }
  }
}

// ---------------- finalize: loss + prec1 ----------------
__global__ void k_final(const float* __restrict__ sumexp, const u64* __restrict__ packed,
                        const float* __restrict__ phi, const int* __restrict__ label,
                        float* __restrict__ out){
  int i = threadIdx.x;  // 512 threads, one row each
  float lse  = S_ + logf(sumexp[i]);
  float loss = lse - S_ * phi[i];
  u32 pred = ~(u32)(packed[i] & 0xFFFFFFFFull);
  float corr = (pred == (u32)label[i]) ? 1.f : 0.f;
  float a = loss, b = corr;
  #pragma unroll
  for (int off = 1; off < 64; off <<= 1){ a += __shfl_xor(a, off); b += __shfl_xor(b, off); }
  __shared__ float sa[8], sb[8];
  if ((i & 63) == 0){ sa[i >> 6] = a; sb[i >> 6] = b; }
  __syncthreads();
  if (i == 0){
    float ta = 0.f, tb = 0.f;
    #pragma unroll
    for (int j = 0; j < 8; ++j){ ta += sa[j]; tb += sb[j]; }
    out[0] = ta / 512.f;
    out[1] = tb * (100.f / 512.f);
  }
}

extern "C" void kernel_launch(void* const* d_in, const int* in_sizes, int n_in,
                              void* d_out, int out_size, void* d_ws, size_t ws_size,
                              hipStream_t stream){
  const float* x     = (const float*)d_in[0];
  const int*   label = (const int*)d_in[1];
  const float* w     = (const float*)d_in[2];
  float* out = (float*)d_out;
  char* ws = (char*)d_ws;

  unsigned short* xn = (unsigned short*)ws;            // 512*512*2 = 524288 B
  float* sumexp = (float*)(ws + 524288);               // 2048 B
  u64*   packed = (u64*)(ws + 524288 + 2048);          // 4096 B
  float* phi    = (float*)(ws + 524288 + 2048 + 4096); // 2048 B

  k_init <<<1,   512, 0, stream>>>(sumexp, packed, phi);
  k_normx<<<128, 256, 0, stream>>>(x, xn);
  k_gemm <<<(CK_/BN)*4, 256, 0, stream>>>(xn, w, label, sumexp, packed, phi);
  k_final<<<1,   512, 0, stream>>>(sumexp, packed, phi, label, out);
}

// Round 2
// 479.067 us; speedup vs baseline: 1.7077x; 1.7077x over previous
//
#include <hip/hip_runtime.h>
#include <stdint.h>

#define B_ 512
#define D_ 512
#define C_ 100000
#define CK_ 300000
#define S_ 30.0f
#define COSM_ 0.8775825618903728f
#define SINM_ 0.4794255386042030f
#define TH_ (-0.8775825618903728f)
#define MM_ 0.2397127693021015f
#define EPS_ 1e-12f

#define BM 128
#define BN 96
#define BK 32

typedef float f32x4 __attribute__((ext_vector_type(4)));
typedef short s16x8 __attribute__((ext_vector_type(8)));
typedef unsigned long long u64;
typedef unsigned int u32;

__device__ __forceinline__ unsigned short f2bf(float f){
  u32 u = __float_as_uint(f);
  u += 0x7FFFu + ((u >> 16) & 1u);   // round-to-nearest-even
  return (unsigned short)(u >> 16);
}

// ---------------- normalize x rows -> bf16 ----------------
__global__ void k_normx(const float* __restrict__ x, unsigned short* __restrict__ xn){
  int row  = blockIdx.x * 4 + (threadIdx.x >> 6);
  int lane = threadIdx.x & 63;
  const float* xr = x + (size_t)row * D_ + lane * 8;
  float4 v0 = *(const float4*)xr;
  float4 v1 = *(const float4*)(xr + 4);
  float s = v0.x*v0.x + v0.y*v0.y + v0.z*v0.z + v0.w*v0.w
          + v1.x*v1.x + v1.y*v1.y + v1.z*v1.z + v1.w*v1.w;
  #pragma unroll
  for (int off = 1; off < 64; off <<= 1) s += __shfl_xor(s, off);
  float inv = 1.f / fmaxf(sqrtf(s), EPS_);
  s16x8 h;
  h[0] = (short)f2bf(v0.x*inv); h[1] = (short)f2bf(v0.y*inv);
  h[2] = (short)f2bf(v0.z*inv); h[3] = (short)f2bf(v0.w*inv);
  h[4] = (short)f2bf(v1.x*inv); h[5] = (short)f2bf(v1.y*inv);
  h[6] = (short)f2bf(v1.z*inv); h[7] = (short)f2bf(v1.w*inv);
  *(s16x8*)(xn + (size_t)row * D_ + lane * 8) = h;
}

// ---------------- zero the per-row reduction buffers ----------------
__global__ void k_init(float* __restrict__ sumexp, u64* __restrict__ packed,
                       float* __restrict__ phi){
  int i = threadIdx.x;
  sumexp[i] = 0.f;
  packed[i] = 0ull;
  phi[i]    = 0.f;
}

// ---------------- fused GEMM + norm + subcenter-max + lse/argmax ----------------
__global__ __launch_bounds__(256, 4) void k_gemm(
    const unsigned short* __restrict__ xn, const float* __restrict__ w,
    const int* __restrict__ label,
    float* __restrict__ sumexp_g, u64* __restrict__ packed_g,
    float* __restrict__ phi_g)
{
  // staging tiles (bf16, XOR-swizzled 16B slots) unioned with the epilogue mx tile
  __shared__ union {
    struct { unsigned short a[BM*BK]; unsigned short b[BN*BK]; } st; // 14336 B
    float mx[BM*34];                                                 // 17408 B
  } sm;
  __shared__ float invs[BN];
  __shared__ int   slab[BM];

  // bijective XCD-chunked mapping (12500 blocks, 8 XCDs: q=1562, r=4).
  // The 4 row-tiles sharing one weight column-tile become consecutive on ONE XCD.
  const int bid = blockIdx.x;
  const int xcd = bid & 7;
  const int i8  = bid >> 3;
  const int seq = (xcd < 4) ? (xcd*1563 + i8) : (6252 + (xcd-4)*1562 + i8);
  const int ct = seq >> 2;                 // column tile 0..3124
  const int rt = seq & 3;                  // row tile 0..3
  const int rowbase = rt * BM;
  const int colbase = ct * BN;

  const int tid  = threadIdx.x;
  const int lane = tid & 63;
  const int wid  = tid >> 6;
  const int wm   = wid >> 1, wn = wid & 1; // 2x2 wave grid, wave tile 64x48
  const int lc15 = lane & 15, lhi = lane >> 4;

  if (tid < BM) slab[tid] = label[rowbase + tid];

  // ---- precompute staging pointers (kt-invariant) ----
  // A: 128x32 bf16, 2 passes x 256 threads x 16B. slot swizzle: slot^((row>>1)&3)
  const unsigned short* asrc[2]; int adst[2];
  #pragma unroll
  for (int p = 0; p < 2; ++p){
    int s = p*256 + tid;
    int row = s >> 2, slot = s & 3;
    asrc[p] = xn + (size_t)(rowbase + row) * D_ + slot*8;
    adst[p] = row*32 + ((slot ^ ((row>>1)&3)) << 3);
  }
  // B: 96 positions x 32 cols fp32, 3 passes x 256 threads x 16B.
  // COLUMN PERMUTATION: tile position p=(wnp*48 + j*16 + c) <-> weight row (class wnp*16+c, subcenter j)
  const float* bsrc[3]; int bdst[3];
  #pragma unroll
  for (int p = 0; p < 3; ++p){
    int fl  = p*256 + tid;
    int pos = fl >> 3;              // 0..95 tile position
    int fc  = (fl & 7) * 4;         // float col 0..28
    int wnp = pos / 48;
    int rem = pos - wnp*48;
    int j   = rem >> 4, c = rem & 15;
    int wrow = colbase + (wnp*16 + c)*3 + j;
    bsrc[p] = w + (size_t)wrow * D_ + fc;
    int slot = fc >> 3, half8 = (fc >> 2) & 1;
    bdst[p] = pos*32 + ((slot ^ ((pos>>1)&3)) << 3) + half8*4;
  }
  // fragment read offsets (swizzled); row base is a multiple of 16 so (row>>1)&3 == (lc15>>1)&3
  const int sx = (lc15 >> 1) & 3;
  int swzA[4], swzB[3];
  #pragma unroll
  for (int m = 0; m < 4; ++m) swzA[m] = (wm*64 + m*16 + lc15)*32 + ((lhi ^ sx) << 3);
  #pragma unroll
  for (int n = 0; n < 3; ++n) swzB[n] = (wn*48 + n*16 + lc15)*32 + ((lhi ^ sx) << 3);

  f32x4 acc[4][3] = {};
  float sq[3] = {0.f, 0.f, 0.f};

  for (int kt = 0; kt < D_/BK; ++kt){
    const int k0 = kt * BK;
    #pragma unroll
    for (int p = 0; p < 2; ++p){
      s16x8 v = *(const s16x8*)(asrc[p] + k0);
      *(s16x8*)(&sm.st.a[adst[p]]) = v;
    }
    #pragma unroll
    for (int p = 0; p < 3; ++p){
      float4 v = *(const float4*)(bsrc[p] + k0);
      sq[p] += v.x*v.x + v.y*v.y + v.z*v.z + v.w*v.w;
      ushort4 h;
      h.x = f2bf(v.x); h.y = f2bf(v.y); h.z = f2bf(v.z); h.w = f2bf(v.w);
      *(ushort4*)(&sm.st.b[bdst[p]]) = h;
    }
    __syncthreads();
    s16x8 af[4], bfr[3];
    #pragma unroll
    for (int m = 0; m < 4; ++m) af[m]  = *(const s16x8*)(&sm.st.a[swzA[m]]);
    #pragma unroll
    for (int n = 0; n < 3; ++n) bfr[n] = *(const s16x8*)(&sm.st.b[swzB[n]]);
    #pragma unroll
    for (int m = 0; m < 4; ++m)
      #pragma unroll
      for (int n = 0; n < 3; ++n)
        acc[m][n] = __builtin_amdgcn_mfma_f32_16x16x32_bf16(af[m], bfr[n], acc[m][n], 0, 0, 0);
    __syncthreads();
  }

  // weight-row inverse norms (position space): each position's sumsq is spread over 8 adjacent threads
  #pragma unroll
  for (int p = 0; p < 3; ++p){
    float s = sq[p];
    s += __shfl_xor(s, 1); s += __shfl_xor(s, 2); s += __shfl_xor(s, 4);
    if ((tid & 7) == 0) invs[(p*256 + tid) >> 3] = 1.f / fmaxf(sqrtf(s), EPS_);
  }
  __syncthreads();

  // in-register subcenter max (3 n-fragments = 3 subcenters of the SAME class), phi at label, write mx
  {
    float inv0 = invs[wn*48 +  0 + lc15];
    float inv1 = invs[wn*48 + 16 + lc15];
    float inv2 = invs[wn*48 + 32 + lc15];
    int cls    = wn*16 + lc15;            // local class 0..31
    int lcbase = ct * 32;
    #pragma unroll
    for (int m = 0; m < 4; ++m){
      #pragma unroll
      for (int r = 0; r < 4; ++r){
        int rl = wm*64 + m*16 + lhi*4 + r;
        float v = fmaxf(fmaxf(acc[m][0][r]*inv0, acc[m][1][r]*inv1), acc[m][2][r]*inv2);
        if (slab[rl] - lcbase == cls){
          float cy = v;
          float s2 = fminf(fmaxf(1.f - cy*cy, 0.f), 1.f);
          float sy = sqrtf(s2);
          float ph = cy*COSM_ - sy*SINM_;
          if (!(cy - TH_ > 0.f)) ph = cy - MM_;
          phi_g[rowbase + rl] = ph;       // unique writer
          v = ph;
        }
        sm.mx[rl*34 + cls] = v;
      }
    }
  }
  __syncthreads();

  // per-row reduction over the 32 classes: 2 threads per row
  {
    int row  = tid >> 1;
    int half = tid & 1;
    int grow = rowbase + row;
    float se = 0.f;
    u64 pk = 0ull;
    #pragma unroll
    for (int c = 0; c < 16; ++c){
      int lc = half*16 + c;
      float v = sm.mx[row*34 + lc];
      se += __expf(S_*v - S_);            // shift by 30 (= S*max possible cos)
      u32 u = __float_as_uint(v);
      u = (v >= 0.f) ? (u | 0x80000000u) : ~u;            // sortable float
      u64 p = ((u64)u << 32) | (u32)~(u32)(ct*32 + lc);   // ~idx: first-occurrence ties
      pk = (p > pk) ? p : pk;
    }
    se += __shfl_xor(se, 1);
    u32 lo = (u32)pk, hi = (u32)(pk >> 32);
    u32 plo = __shfl_xor(lo, 1), phi2 = __shfl_xor(hi, 1);
    u64 po = ((u64)phi2 << 32) | plo;
    pk = (po > pk) ? po : pk;
    if (half == 0){
      atomicAdd(&sumexp_g[grow], se);
      atomicMax(&packed_g[grow], pk);
    }
  }
}

// ---------------- finalize: loss + prec1 ----------------
__global__ void k_final(const float* __restrict__ sumexp, const u64* __restrict__ packed,
                        const float* __restrict__ phi, const int* __restrict__ label,
                        float* __restrict__ out){
  int i = threadIdx.x;  // 512 threads, one row each
  float lse  = S_ + logf(sumexp[i]);
  float loss = lse - S_ * phi[i];
  u32 pred = ~(u32)(packed[i] & 0xFFFFFFFFull);
  float corr = (pred == (u32)label[i]) ? 1.f : 0.f;
  float a = loss, b = corr;
  #pragma unroll
  for (int off = 1; off < 64; off <<= 1){ a += __shfl_xor(a, off); b += __shfl_xor(b, off); }
  __shared__ float sa[8], sb[8];
  if ((i & 63) == 0){ sa[i >> 6] = a; sb[i >> 6] = b; }
  __syncthreads();
  if (i == 0){
    float ta = 0.f, tb = 0.f;
    #pragma unroll
    for (int j = 0; j < 8; ++j){ ta += sa[j]; tb += sb[j]; }
    out[0] = ta / 512.f;
    out[1] = tb * (100.f / 512.f);
  }
}

extern "C" void kernel_launch(void* const* d_in, const int* in_sizes, int n_in,
                              void* d_out, int out_size, void* d_ws, size_t ws_size,
                              hipStream_t stream){
  const float* x     = (const float*)d_in[0];
  const int*   label = (const int*)d_in[1];
  const float* w     = (const float*)d_in[2];
  float* out = (float*)d_out;
  char* ws = (char*)d_ws;

  unsigned short* xn = (unsigned short*)ws;            // 512*512*2 = 524288 B
  float* sumexp = (float*)(ws + 524288);               // 2048 B
  u64*   packed = (u64*)(ws + 524288 + 2048);          // 4096 B
  float* phi    = (float*)(ws + 524288 + 2048 + 4096); // 2048 B

  k_init <<<1,   512, 0, stream>>>(sumexp, packed, phi);
  k_normx<<<128, 256, 0, stream>>>(x, xn);
  k_gemm <<<(CK_/BN)*4, 256, 0, stream>>>(xn, w, label, sumexp, packed, phi);
  k_final<<<1,   512, 0, stream>>>(sumexp, packed, phi, label, out);
}